// Round 8
// baseline (200.833 us; speedup 1.0000x reference)
//
#include <hip/hip_runtime.h>
#include <math.h>

#define D_MELS 80
#define F4ROW  20          // float4 per row
#define T_DIM  4000
#define NQM    7           // main-kernel quantities: 0=l1 1=bandextra 2=diff2 3=tgt2 4=energy 5=delta 6=delta2
#define NTHR   256
#define RPI    14          // rows CONTRIBUTED per tile (16 loaded, 2 overlap)

// ---------------- flags + mask-count pre-kernel ----------------
// One WAVE per main-block: computes (a) bflag[g] = any(mask!=0) over the rows
// that main-block g will LOAD (halo included), (b) partial mask-count sums
// (m, m*m1, m*m1*m2) over the rows it OWNS. This moves the main kernel's
// gate off the vector-load latency path (scalar K$ load instead).
__global__ __launch_bounds__(NTHR) void mel_flags(
    const float* __restrict__ mask, int* __restrict__ bflag,
    float* __restrict__ cpart, int BT, int nmb, int rowsPerMB, int nfb)
{
    const int tid  = threadIdx.x;
    const int lane = tid & 63;
    const int wv   = tid >> 6;
    const int g    = blockIdx.x * (NTHR / 64) + wv;   // main-block id

    float cm = 0.f, cdm = 0.f, cd2m = 0.f;
    int   fl = 0;

    if (g < nmb) {
        const int rlo = g * rowsPerMB;
        int rhi = rlo + rowsPerMB; if (rhi > BT) rhi = BT;
        for (int r = rlo - 2 + lane; r < rhi; r += 64) {
            if (r < 0) continue;
            float m = mask[r];
            fl |= (m != 0.f);
            if (r >= rlo && m != 0.f) {           // counts only over owned rows
                int t = r % T_DIM;
                cm += m;
                if (t >= 1) {
                    float m1 = mask[r - 1];
                    cdm += m * m1;
                    if (t >= 2) cd2m += m * m1 * mask[r - 2];
                }
            }
        }
    }

    // wave-uniform reductions
    const bool anyl = __any(fl != 0);
    #pragma unroll
    for (int off = 32; off > 0; off >>= 1) {
        cm   += __shfl_down(cm,   off, 64);
        cdm  += __shfl_down(cdm,  off, 64);
        cd2m += __shfl_down(cd2m, off, 64);
    }
    if (g < nmb && lane == 0) bflag[g] = anyl ? 1 : 0;

    __shared__ float cred[NTHR / 64][3];
    if (lane == 0) { cred[wv][0] = cm; cred[wv][1] = cdm; cred[wv][2] = cd2m; }
    __syncthreads();
    if (tid < 3) {
        float s = 0.f;
        #pragma unroll
        for (int w2 = 0; w2 < NTHR / 64; ++w2) s += cred[w2][tid];
        cpart[tid * nfb + blockIdx.x] = s;
    }
}

// ---------------- main kernel ----------------
// Per wave-tile: ONE burst of 11 independent loads (mask + 5 pred + 5 tgt
// float4s), no load-gating branch before issue — the dead-block skip is a
// scalar bflag load (K$), the dead-tile-within-live-block check runs AFTER
// the burst is in flight. Removes the mask->data latency serialization that
// R0-R7 all carried (LLC-resident dispatches proved time is latency/convoy
// -bound, not HBM-bound).
__global__ __launch_bounds__(NTHR, 4) void mel_loss_main(
    const float* __restrict__ pred, const float* __restrict__ tgt,
    const float* __restrict__ mask, const int* __restrict__ bflag,
    float* __restrict__ partial, int BT, int Jtot, int K, int nmb)
{
    const int tid = threadIdx.x;

    if (!bflag[blockIdx.x]) {                    // scalar load, uniform branch
        if (tid < NQM) partial[tid * nmb + blockIdx.x] = 0.f;
        return;
    }

    const int lane = tid & 63;
    const int qtr  = lane & 3;        // float4-quarter of row (5 float4s per lane)
    const int rw   = lane >> 2;       // row within 16-row tile
    const int wv   = tid >> 6;
    const int gw   = blockIdx.x * (NTHR / 64) + wv;

    const float4* p4 = (const float4*)pred;
    const float4* q4 = (const float4*)tgt;
    const int lsrc4 = (lane - 4) & 63;   // lane holding row r-1 (same qtr)
    const int lsrc8 = (lane - 8) & 63;   // lane holding row r-2 (same qtr)

    float v_l1 = 0.f, v_frr = 0.f, v_diff2 = 0.f, v_tgt2 = 0.f, v_energy = 0.f;
    float v_d = 0.f, v_d2 = 0.f;

    const int j0 = gw * K;
    for (int s = 0; s < K; ++s) {
        const int j = j0 + s;
        if (j >= Jtot) break;
        const int r = j * RPI - 2 + rw;
        const int rload = r < 0 ? 0 : (r >= BT ? BT - 1 : r);

        // ---- single burst: 11 independent loads, no branch before issue ----
        const size_t rowb = (size_t)rload * F4ROW + qtr;
        float  mload = mask[rload];
        float4 P[5], Q[5];
        #pragma unroll
        for (int k = 0; k < 5; ++k) P[k] = p4[rowb + 4 * k];
        #pragma unroll
        for (int k = 0; k < 5; ++k) Q[k] = q4[rowb + 4 * k];

        // dead-tile-in-live-block: rare (seq boundaries); gates compute only
        if (!__any(mload != 0.0f)) continue;

        const int t = rload % T_DIM;             // for contributing rows, rload == r
        const float m1 = __shfl(mload, lsrc4, 64);   // mask[r-1] (valid where used)
        const float m2 = __shfl(mload, lsrc8, 64);   // mask[r-2]
        const bool contrib = (rw >= 2) && (r < BT);
        const float mt   = contrib ? mload : 0.f;
        const float dmv  = (t >= 1) ? mt * m1 : 0.f; // t-gating kills seq-boundary garbage
        const float d2mv = (t >= 2) ? dmv * m2 : 0.f;

        float l1r = 0.f, frr = 0.f, sqr = 0.f, t2r = 0.f, er = 0.f, dr = 0.f, d2r = 0.f;
        #pragma unroll
        for (int k = 0; k < 5; ++k) {
            float e0 = P[k].x - Q[k].x, e1 = P[k].y - Q[k].y,
                  e2 = P[k].z - Q[k].z, e3 = P[k].w - Q[k].w;

            // e of row r-1 / r-2 live in neighbor lanes of THIS tile — no reload
            float f0 = __shfl(e0, lsrc4, 64);
            float f1 = __shfl(e1, lsrc4, 64);
            float f2 = __shfl(e2, lsrc4, 64);
            float f3 = __shfl(e3, lsrc4, 64);
            float g0 = __shfl(e0, lsrc8, 64);
            float g1 = __shfl(e1, lsrc8, 64);
            float g2 = __shfl(e2, lsrc8, 64);
            float g3 = __shfl(e3, lsrc8, 64);

            float a0 = fabsf(e0), a1 = fabsf(e1), a2 = fabsf(e2), a3 = fabsf(e3);
            l1r += a0 + a1 + a2 + a3;
            // band extra (+1) on d in [10,50); d = 16k + 4qtr + c, branchless range test
            const int d0 = (k << 4) + (qtr << 2);
            frr += ((unsigned)(d0 + 0 - 10) < 40u ? a0 : 0.f)
                 + ((unsigned)(d0 + 1 - 10) < 40u ? a1 : 0.f)
                 + ((unsigned)(d0 + 2 - 10) < 40u ? a2 : 0.f)
                 + ((unsigned)(d0 + 3 - 10) < 40u ? a3 : 0.f);
            sqr += e0 * e0 + e1 * e1 + e2 * e2 + e3 * e3;
            t2r += Q[k].x * Q[k].x + Q[k].y * Q[k].y + Q[k].z * Q[k].z + Q[k].w * Q[k].w;
            er  += e0 + e1 + e2 + e3;
            dr  += fabsf(e0 - f0) + fabsf(e1 - f1) + fabsf(e2 - f2) + fabsf(e3 - f3);
            d2r += fabsf(e0 - 2.f * f0 + g0) + fabsf(e1 - 2.f * f1 + g1)
                 + fabsf(e2 - 2.f * f2 + g2) + fabsf(e3 - 2.f * f3 + g3);
        }

        v_l1    += l1r * mt;
        v_frr   += frr * mt;
        v_diff2 += sqr * mt;
        v_tgt2  += t2r * mt;
        v_d     += dr * dmv;
        v_d2    += d2r * d2mv;

        // row-sum of e within the quad (qtr 0..3 share rw)
        er += __shfl_xor(er, 1, 64);
        er += __shfl_xor(er, 2, 64);
        if (qtr == 0) v_energy += fabsf(er) * mt;
    }

    // ---- block reduction: wave shuffle -> LDS -> per-block store ----
    float vals[NQM] = {v_l1, v_frr, v_diff2, v_tgt2, v_energy, v_d, v_d2};
    #pragma unroll
    for (int q = 0; q < NQM; ++q) {
        float v = vals[q];
        #pragma unroll
        for (int off = 32; off > 0; off >>= 1)
            v += __shfl_down(v, off, 64);
        vals[q] = v;
    }
    __shared__ float red[NTHR / 64][NQM];
    if (lane == 0) {
        #pragma unroll
        for (int q = 0; q < NQM; ++q) red[wv][q] = vals[q];
    }
    __syncthreads();
    if (tid < NQM) {
        float s = 0.f;
        #pragma unroll
        for (int w2 = 0; w2 < NTHR / 64; ++w2) s += red[w2][tid];
        partial[tid * nmb + blockIdx.x] = s;
    }
}

// ---------------- finalize ----------------
__global__ __launch_bounds__(640) void mel_loss_finalize(
    const float* __restrict__ partial, const float* __restrict__ cpart,
    const float* __restrict__ w, float* __restrict__ out, int nmb, int nfb)
{
    const int tid = threadIdx.x;
    const int wv  = tid >> 6;        // 0..6 main quantities; 7..9 mask counts
    const int lane = tid & 63;
    __shared__ float fin[10];

    float s = 0.f;
    if (wv < NQM) {
        for (int i = lane; i < nmb; i += 64) s += partial[wv * nmb + i];
    } else {
        for (int i = lane; i < nfb; i += 64) s += cpart[(wv - NQM) * nfb + i];
    }
    #pragma unroll
    for (int off = 32; off > 0; off >>= 1) s += __shfl_down(s, off, 64);
    if (lane == 0 && wv < 10) fin[wv] = s;
    __syncthreads();

    if (tid == 0) {
        float l1s = fin[0], frrs = fin[1], diff2 = fin[2], tgt2 = fin[3];
        float energys = fin[4], ds = fin[5], d2s = fin[6];
        float ms = fin[7], dms = fin[8], d2ms = fin[9];

        float wsum = 0.f;
        for (int d = 0; d < D_MELS; ++d) wsum += w[d];
        float wmean = wsum / (float)D_MELS;

        float n1  = fmaxf(ms   * (float)D_MELS, 1.f);
        float nd  = fmaxf(dms  * (float)D_MELS, 1.f);
        float nd2 = fmaxf(d2ms * (float)D_MELS, 1.f);

        float l1_loss     = l1s / n1;
        float delta_loss  = ds / nd;
        float delta2_loss = d2s / nd2;
        float sc_num = sqrtf(diff2 / n1);
        float sc_den = fmaxf(sqrtf(tgt2 / n1), 1e-8f);
        float sc_loss = sc_num / sc_den;
        float band_loss = ((l1s + frrs) / n1) / wmean;
        float energy_loss = (energys / (float)D_MELS) / fmaxf(ms, 1.f);

        out[0] = 1.0f * l1_loss + 0.5f * delta_loss + 0.25f * delta2_loss
               + 0.5f * sc_loss + 1.0f * band_loss + 0.5f * energy_loss;
    }
}

extern "C" void kernel_launch(void* const* d_in, const int* in_sizes, int n_in,
                              void* d_out, int out_size, void* d_ws, size_t ws_size,
                              hipStream_t stream) {
    const float* pred = (const float*)d_in[0];
    const float* tgt  = (const float*)d_in[1];
    const float* mask = (const float*)d_in[2];
    const float* w    = (const float*)d_in[3];
    int BT = in_sizes[2];                         // B*T = 256000

    int Jtot = (BT + RPI - 1) / RPI;              // 18286 14-row tiles

    // choose K (tiles per wave) so workspace fits: partial[7*nmb] + cpart[3*nfb] + bflag[nmb]
    int K, nmb, nfb;
    size_t need;
    for (K = 1;; K *= 2) {
        int nwaves = (Jtot + K - 1) / K;
        nmb = (nwaves + (NTHR / 64) - 1) / (NTHR / 64);
        nfb = (nmb + (NTHR / 64) - 1) / (NTHR / 64);
        need = (size_t)(NQM * nmb + 3 * nfb) * sizeof(float) + (size_t)nmb * sizeof(int);
        if (need <= ws_size || K >= Jtot) break;
    }
    const int rowsPerMB = (NTHR / 64) * K * RPI;  // rows owned per main block

    float* partial = (float*)d_ws;
    float* cpart   = partial + NQM * nmb;
    int*   bflag   = (int*)(cpart + 3 * nfb);

    mel_flags<<<nfb, NTHR, 0, stream>>>(mask, bflag, cpart, BT, nmb, rowsPerMB, nfb);
    mel_loss_main<<<nmb, NTHR, 0, stream>>>(pred, tgt, mask, bflag, partial, BT, Jtot, K, nmb);
    mel_loss_finalize<<<1, 640, 0, stream>>>(partial, cpart, w, (float*)d_out, nmb, nfb);
}

// Round 11
// 193.067 us; speedup vs baseline: 1.0402x; 1.0402x over previous
//
#include <hip/hip_runtime.h>
#include <math.h>

#define D_MELS 80
#define F4ROW  20          // float4 per row
#define T_DIM  4000
#define NQM    7           // main quantities: 0=l1 1=bandextra 2=diff2 3=tgt2 4=energy 5=delta 6=delta2
#define NTHR   256
#define RPI    14          // rows CONTRIBUTED per tile (16 loaded, 2 overlap)

// ---- DPP helpers: cross-lane moves on the VALU pipe, NOT the DS pipe ----
// Direction semantics (verified against the GPUOpen cross-lane reduction
// idiom, which accumulates into lane 63 via row_shr):
//   row_shr:N  -> lane i reads lane i-N   (use for r-1 / r-2 neighbors)
//   row_shl:N  -> lane i reads lane i+N   (use to accumulate sums into lane 0)
// bound_ctrl=true zero-fills out-of-row sources: for row_shr:1/2 these are
// lanes rw<1/2 — exactly the halo rows our masks already exclude.
template<int CTRL>
__device__ __forceinline__ float dppf(float v) {
    return __int_as_float(__builtin_amdgcn_update_dpp(
        0, __float_as_int(v), CTRL, 0xF, 0xF, true));
}
#define ROW_SHL1 0x101
#define ROW_SHL2 0x102
#define ROW_SHL4 0x104
#define ROW_SHL8 0x108
#define ROW_SHR1 0x111
#define ROW_SHR2 0x112

// 64-lane sum into lane 0: 4 DPP row_shl steps (VALU; row total lands in
// lane 0 of each 16-lane DPP row) + 2 cross-row shuffles (DS).
__device__ __forceinline__ float wave_sum(float v) {
    v += dppf<ROW_SHL8>(v);
    v += dppf<ROW_SHL4>(v);
    v += dppf<ROW_SHL2>(v);
    v += dppf<ROW_SHL1>(v);            // lane 0 of each row = row sum
    v += __shfl_xor(v, 16, 64);
    v += __shfl_xor(v, 32, 64);        // lane 0 = full wave sum
    return v;
}

// ---------------- flags + mask-count pre-kernel (unchanged from R8) ----------------
__global__ __launch_bounds__(NTHR) void mel_flags(
    const float* __restrict__ mask, int* __restrict__ bflag,
    float* __restrict__ cpart, int BT, int nmb, int rowsPerMB, int nfb)
{
    const int tid  = threadIdx.x;
    const int lane = tid & 63;
    const int wv   = tid >> 6;
    const int g    = blockIdx.x * (NTHR / 64) + wv;   // main-block id

    float cm = 0.f, cdm = 0.f, cd2m = 0.f;
    int   fl = 0;

    if (g < nmb) {
        const int rlo = g * rowsPerMB;
        int rhi = rlo + rowsPerMB; if (rhi > BT) rhi = BT;
        for (int r = rlo - 2 + lane; r < rhi; r += 64) {
            if (r < 0) continue;
            float m = mask[r];
            fl |= (m != 0.f);
            if (r >= rlo && m != 0.f) {
                int t = r % T_DIM;
                cm += m;
                if (t >= 1) {
                    float m1 = mask[r - 1];
                    cdm += m * m1;
                    if (t >= 2) cd2m += m * m1 * mask[r - 2];
                }
            }
        }
    }

    const bool anyl = __any(fl != 0);
    #pragma unroll
    for (int off = 32; off > 0; off >>= 1) {
        cm   += __shfl_down(cm,   off, 64);
        cdm  += __shfl_down(cdm,  off, 64);
        cd2m += __shfl_down(cd2m, off, 64);
    }
    if (g < nmb && lane == 0) bflag[g] = anyl ? 1 : 0;

    __shared__ float cred[NTHR / 64][3];
    if (lane == 0) { cred[wv][0] = cm; cred[wv][1] = cdm; cred[wv][2] = cd2m; }
    __syncthreads();
    if (tid < 3) {
        float s = 0.f;
        #pragma unroll
        for (int w2 = 0; w2 < NTHR / 64; ++w2) s += cred[w2][tid];
        cpart[tid * nfb + blockIdx.x] = s;
    }
}

// ---------------- main kernel ----------------
// Lane mapping: rw = lane&15 (row within tile, aligned to DPP rows),
// qtr = lane>>4 (float4-column group). Neighbor rows r-1/r-2 are lanes
// l-1/l-2 in the SAME DPP row -> f/g/m1/m2 via row_shr DPP (VALU pipe).
// DS ops per tile: ~86 (R8) -> ~10 (2 energy shuffles + amortized epilogue).
__global__ __launch_bounds__(NTHR, 4) void mel_loss_main(
    const float* __restrict__ pred, const float* __restrict__ tgt,
    const float* __restrict__ mask, const int* __restrict__ bflag,
    float* __restrict__ partial, int BT, int Jtot, int K, int nmb)
{
    const int tid = threadIdx.x;

    if (!bflag[blockIdx.x]) {                    // scalar load, uniform branch
        if (tid < NQM) partial[tid * nmb + blockIdx.x] = 0.f;
        return;
    }

    const int lane = tid & 63;
    const int qtr  = lane >> 4;       // float4-column group 0..3
    const int rw   = lane & 15;       // row within 16-row tile (DPP-row lane)
    const int wv   = tid >> 6;
    const int gw   = blockIdx.x * (NTHR / 64) + wv;

    const float4* p4 = (const float4*)pred;
    const float4* q4 = (const float4*)tgt;

    float v_l1 = 0.f, v_frr = 0.f, v_diff2 = 0.f, v_tgt2 = 0.f, v_energy = 0.f;
    float v_d = 0.f, v_d2 = 0.f;

    const int j0 = gw * K;
    for (int s = 0; s < K; ++s) {
        const int j = j0 + s;
        if (j >= Jtot) break;
        const int r = j * RPI - 2 + rw;
        const int rload = r < 0 ? 0 : (r >= BT ? BT - 1 : r);

        // burst: mask + 10 float4 loads, no branch before issue
        const size_t rowb = (size_t)rload * F4ROW + qtr;
        float  mload = mask[rload];
        float4 P[5], Q[5];
        #pragma unroll
        for (int k = 0; k < 5; ++k) P[k] = p4[rowb + 4 * k];
        #pragma unroll
        for (int k = 0; k < 5; ++k) Q[k] = q4[rowb + 4 * k];

        if (!__any(mload != 0.0f)) continue;     // dead tile inside live block

        const int t = rload % T_DIM;             // for contributing rows, rload == r
        const float m1 = dppf<ROW_SHR1>(mload);  // mask[r-1] (lane rw-1), VALU-DPP
        const float m2 = dppf<ROW_SHR2>(mload);  // mask[r-2] (lane rw-2)
        const bool contrib = (rw >= 2) && (r < BT);
        const float mt   = contrib ? mload : 0.f;
        const float dmv  = (t >= 1) ? mt * m1 : 0.f;  // t-gating kills seq-boundary garbage
        const float d2mv = (t >= 2) ? dmv * m2 : 0.f;

        float l1r = 0.f, frr = 0.f, sqr = 0.f, t2r = 0.f, er = 0.f, dr = 0.f, d2r = 0.f;
        #pragma unroll
        for (int k = 0; k < 5; ++k) {
            float e0 = P[k].x - Q[k].x, e1 = P[k].y - Q[k].y,
                  e2 = P[k].z - Q[k].z, e3 = P[k].w - Q[k].w;

            // e of rows r-1 / r-2 from lower lanes via row_shr DPP (VALU, 0 DS)
            float f0 = dppf<ROW_SHR1>(e0), f1 = dppf<ROW_SHR1>(e1),
                  f2 = dppf<ROW_SHR1>(e2), f3 = dppf<ROW_SHR1>(e3);
            float g0 = dppf<ROW_SHR2>(e0), g1 = dppf<ROW_SHR2>(e1),
                  g2 = dppf<ROW_SHR2>(e2), g3 = dppf<ROW_SHR2>(e3);

            float a0 = fabsf(e0), a1 = fabsf(e1), a2 = fabsf(e2), a3 = fabsf(e3);
            l1r += a0 + a1 + a2 + a3;
            // band extra (+1) on d in [10,50); d = 16k + 4qtr + c
            const int d0 = (k << 4) + (qtr << 2);
            frr += ((unsigned)(d0 + 0 - 10) < 40u ? a0 : 0.f)
                 + ((unsigned)(d0 + 1 - 10) < 40u ? a1 : 0.f)
                 + ((unsigned)(d0 + 2 - 10) < 40u ? a2 : 0.f)
                 + ((unsigned)(d0 + 3 - 10) < 40u ? a3 : 0.f);
            sqr += e0 * e0 + e1 * e1 + e2 * e2 + e3 * e3;
            t2r += Q[k].x * Q[k].x + Q[k].y * Q[k].y + Q[k].z * Q[k].z + Q[k].w * Q[k].w;
            er  += e0 + e1 + e2 + e3;
            dr  += fabsf(e0 - f0) + fabsf(e1 - f1) + fabsf(e2 - f2) + fabsf(e3 - f3);
            d2r += fabsf(e0 - 2.f * f0 + g0) + fabsf(e1 - 2.f * f1 + g1)
                 + fabsf(e2 - 2.f * f2 + g2) + fabsf(e3 - 2.f * f3 + g3);
        }

        v_l1    += l1r * mt;
        v_frr   += frr * mt;
        v_diff2 += sqr * mt;
        v_tgt2  += t2r * mt;
        v_d     += dr * dmv;
        v_d2    += d2r * d2mv;

        // energy: row-sum across the 4 qtr groups (lanes rw, rw+16, rw+32, rw+48)
        er += __shfl_xor(er, 16, 64);
        er += __shfl_xor(er, 32, 64);
        if (qtr == 0) v_energy += fabsf(er) * mt;
    }

    // ---- block reduction: DPP wave sum -> LDS -> per-block store ----
    float vals[NQM] = {v_l1, v_frr, v_diff2, v_tgt2, v_energy, v_d, v_d2};
    #pragma unroll
    for (int q = 0; q < NQM; ++q) vals[q] = wave_sum(vals[q]);

    __shared__ float red[NTHR / 64][NQM];
    if (lane == 0) {
        #pragma unroll
        for (int q = 0; q < NQM; ++q) red[wv][q] = vals[q];
    }
    __syncthreads();
    if (tid < NQM) {
        float s = 0.f;
        #pragma unroll
        for (int w2 = 0; w2 < NTHR / 64; ++w2) s += red[w2][tid];
        partial[tid * nmb + blockIdx.x] = s;
    }
}

// ---------------- finalize (unchanged from R8) ----------------
__global__ __launch_bounds__(640) void mel_loss_finalize(
    const float* __restrict__ partial, const float* __restrict__ cpart,
    const float* __restrict__ w, float* __restrict__ out, int nmb, int nfb)
{
    const int tid = threadIdx.x;
    const int wv  = tid >> 6;        // 0..6 main quantities; 7..9 mask counts
    const int lane = tid & 63;
    __shared__ float fin[10];

    float s = 0.f;
    if (wv < NQM) {
        for (int i = lane; i < nmb; i += 64) s += partial[wv * nmb + i];
    } else {
        for (int i = lane; i < nfb; i += 64) s += cpart[(wv - NQM) * nfb + i];
    }
    #pragma unroll
    for (int off = 32; off > 0; off >>= 1) s += __shfl_down(s, off, 64);
    if (lane == 0 && wv < 10) fin[wv] = s;
    __syncthreads();

    if (tid == 0) {
        float l1s = fin[0], frrs = fin[1], diff2 = fin[2], tgt2 = fin[3];
        float energys = fin[4], ds = fin[5], d2s = fin[6];
        float ms = fin[7], dms = fin[8], d2ms = fin[9];

        float wsum = 0.f;
        for (int d = 0; d < D_MELS; ++d) wsum += w[d];
        float wmean = wsum / (float)D_MELS;

        float n1  = fmaxf(ms   * (float)D_MELS, 1.f);
        float nd  = fmaxf(dms  * (float)D_MELS, 1.f);
        float nd2 = fmaxf(d2ms * (float)D_MELS, 1.f);

        float l1_loss     = l1s / n1;
        float delta_loss  = ds / nd;
        float delta2_loss = d2s / nd2;
        float sc_num = sqrtf(diff2 / n1);
        float sc_den = fmaxf(sqrtf(tgt2 / n1), 1e-8f);
        float sc_loss = sc_num / sc_den;
        float band_loss = ((l1s + frrs) / n1) / wmean;
        float energy_loss = (energys / (float)D_MELS) / fmaxf(ms, 1.f);

        out[0] = 1.0f * l1_loss + 0.5f * delta_loss + 0.25f * delta2_loss
               + 0.5f * sc_loss + 1.0f * band_loss + 0.5f * energy_loss;
    }
}

extern "C" void kernel_launch(void* const* d_in, const int* in_sizes, int n_in,
                              void* d_out, int out_size, void* d_ws, size_t ws_size,
                              hipStream_t stream) {
    const float* pred = (const float*)d_in[0];
    const float* tgt  = (const float*)d_in[1];
    const float* mask = (const float*)d_in[2];
    const float* w    = (const float*)d_in[3];
    int BT = in_sizes[2];                         // B*T = 256000

    int Jtot = (BT + RPI - 1) / RPI;              // 18286 14-row tiles

    // K = tiles per wave (2 amortizes the epilogue DS); grow if ws too small
    int K, nmb, nfb;
    size_t need;
    for (K = 2;; K *= 2) {
        int nwaves = (Jtot + K - 1) / K;
        nmb = (nwaves + (NTHR / 64) - 1) / (NTHR / 64);
        nfb = (nmb + (NTHR / 64) - 1) / (NTHR / 64);
        need = (size_t)(NQM * nmb + 3 * nfb) * sizeof(float) + (size_t)nmb * sizeof(int);
        if (need <= ws_size || K >= Jtot) break;
    }
    const int rowsPerMB = (NTHR / 64) * K * RPI;  // rows owned per main block

    float* partial = (float*)d_ws;
    float* cpart   = partial + NQM * nmb;
    int*   bflag   = (int*)(cpart + 3 * nfb);

    mel_flags<<<nfb, NTHR, 0, stream>>>(mask, bflag, cpart, BT, nmb, rowsPerMB, nfb);
    mel_loss_main<<<nmb, NTHR, 0, stream>>>(pred, tgt, mask, bflag, partial, BT, Jtot, K, nmb);
    mel_loss_finalize<<<1, 640, 0, stream>>>(partial, cpart, w, (float*)d_out, nmb, nfb);
}